// Round 1
// 103.262 us; speedup vs baseline: 1.0077x; 1.0077x over previous
//
#include <hip/hip_runtime.h>
#include <hip/hip_bf16.h>

// Problem constants
#define N_PAIRS   64000
#define N_ATOMS   16000
#define N_FEAT    8
#define N_HIDDEN  100
// Aggregate-first, fused, scalar-metadata phase 1:
//   S[d, f*100+j] = sum_{e: dest(e)=d} pf[e,f] * AF[src_e, j]   (f<8)
//   S[d, 800+j]   = sum_{e: dest(e)=d} AF[src_e, j]             (bias block)
//   out[d,i]      = sum_k S[d,k] * Wbig[k,i]
//   S lives only in LDS. Edge metadata is wave-uniform -> SGPR loads.
//   This revision drops the pfb staging buffer: bucket packs (e<<14)|src so
//   fused reads pf values straight from the dense, L2-hot pair_features
//   array (saves 64000 scattered 32B write-allocate stores in setup and the
//   cold 33MB-region refetch in fused).
#define SW        1024    // wtb2 row stride (stored transposed: wtb2[i][k])
#define SKL       936     // LDS S-tile row stride (bf16)
#define MAX_DEG   32      // bucket stride per dest (P(deg>32|Poisson(4))~1e-18)

#define SETUP_BLOCKS (112 * 1024 / 256)    // 448
#define HIST_BLOCKS  (N_PAIRS / 256)       // 250

typedef __attribute__((ext_vector_type(8))) short bf16x8_t;   // 8 bf16 = 4 VGPRs
typedef __attribute__((ext_vector_type(4))) float f32x4_t;

// ---- setup_hist: blocks [0,448) build wtb2[i][k] = Wbig[k][i] (bf16, padded);
//      blocks [448,698) bucket edges by dest: packed (edge_id<<14)|src.
__global__ __launch_bounds__(256) void setup_hist(const float* __restrict__ W,
                                                  const float* __restrict__ b,
                                                  const int* __restrict__ a2p,
                                                  __hip_bfloat16* __restrict__ wtb2,
                                                  int* __restrict__ deg,
                                                  unsigned* __restrict__ bucket) {
    int bid = blockIdx.x;
    if (bid < SETUP_BLOCKS) {
        int id = bid * 256 + threadIdx.x;      // < 114688
        int i = id >> 10;                      // 0..111 (output col)
        int k = id & 1023;                     // 0..1023 (contraction index)
        float v = 0.f;
        if (i < N_HIDDEN) {
            if (k < 800) {
                int f = k / N_HIDDEN;
                int j = k - f * N_HIDDEN;
                v = W[f * (N_HIDDEN * N_HIDDEN) + i * N_HIDDEN + j];
            } else if (k < 900) {
                int j = k - 800;
                v = b[i * N_HIDDEN + j];
            }
        }
        wtb2[id] = __float2bfloat16(v);
    } else {
        int e = (bid - SETUP_BLOCKS) * 256 + threadIdx.x;   // < 64000 exactly
        int dest = a2p[e * 2];
        int src  = a2p[e * 2 + 1];
        int slot = atomicAdd(&deg[dest], 1);
        if (slot < MAX_DEG)
            bucket[dest * MAX_DEG + slot] = ((unsigned)e << 14) | (unsigned)src;
    }
}

// ---- fused: one block = 16 dest atoms, 512 threads (8 waves).
//      Phase 1: wave w owns tile rows 2w, 2w+1 (serial); per dest the edge
//      loop is WAVE-UNIFORM: packed bucket word via scalar load gives src
//      (af gather address) and edge id (pf scalar loads from dense array);
//      af gathered fp32 float2 by lanes 0..49; batch-4 predicated prefetch,
//      single wait, FMA block with SGPR pf operands. No shfl anywhere.
//      Phase 2: waves 0..6 each do one 16-col n-tile of S_tile @ wtb2^T.
__global__ __launch_bounds__(512) void fused_edge_gemm(const float* __restrict__ af,
                                                       const float* __restrict__ pf,
                                                       const int* __restrict__ deg,
                                                       const unsigned* __restrict__ bucket,
                                                       const __hip_bfloat16* __restrict__ wtb2,
                                                       float* __restrict__ out) {
    __shared__ __hip_bfloat16 St[16 * SKL];            // 29,952 B
    int blk  = blockIdx.x;                             // 0..999
    int wave = threadIdx.x >> 6;
    int lane = threadIdx.x & 63;
    bool act = (lane < 50);                            // cols 2*lane, 2*lane+1

#pragma unroll
    for (int j = 0; j < 2; ++j) {
        int r = wave * 2 + j;                          // tile row 0..15
        int d = __builtin_amdgcn_readfirstlane(blk * 16 + r);   // force SGPR
        int n = deg[d];                                // scalar load
        if (n > MAX_DEG) n = MAX_DEG;                  // P(deg>32|Poisson(4))~1e-18

        const unsigned* sb = bucket + (size_t)d * MAX_DEG;       // SGPR base

        float acc[9][2] = {};                          // f=0..7 weighted, f=8 bias
        for (int t0 = 0; t0 < n; t0 += 4) {
            float2 a[4];
            unsigned pk[4];
#pragma unroll
            for (int u = 0; u < 4; ++u) {
                int t = t0 + u;
                pk[u] = sb[t < n ? t : 0];             // scalar load (clamped)
                int src = (int)(pk[u] & 16383u);       // SGPR
                if (t < n && act)
                    a[u] = *(const float2*)(af + src * N_HIDDEN + 2 * lane);
                else
                    a[u] = make_float2(0.f, 0.f);
            }
#pragma unroll
            for (int u = 0; u < 4; ++u) {
                int e = (int)(pk[u] >> 14);            // SGPR edge id
                const float* pe = pf + e * N_FEAT;     // dense, L2-hot
#pragma unroll
                for (int f = 0; f < N_FEAT; ++f) {
                    float p = pe[f];                   // scalar load -> SGPR operand
                    acc[f][0] += p * a[u].x;
                    acc[f][1] += p * a[u].y;
                }
                acc[8][0] += a[u].x;
                acc[8][1] += a[u].y;
            }
        }

        // write S row to LDS (bf16); lanes 50..63 zero the K-pad cols 900..927
        __hip_bfloat16* srow = St + r * SKL;
        if (act) {
#pragma unroll
            for (int f = 0; f < 9; ++f) {
                __hip_bfloat162 h;
                h.x = __float2bfloat16(acc[f][0]);
                h.y = __float2bfloat16(acc[f][1]);
                *(__hip_bfloat162*)(srow + f * N_HIDDEN + 2 * lane) = h;
            }
        } else if (lane < 64) {
            __hip_bfloat162 z;
            z.x = __float2bfloat16(0.f);
            z.y = z.x;
            *(__hip_bfloat162*)(srow + 900 + 2 * (lane - 50)) = z;   // 900..927
        }
    }
    __syncthreads();

    // ---- phase 2: out[16 rows] = S_tile @ wtb2^T; wave w -> n-tile w (w<7)
    if (wave < 7) {
        int quad = lane >> 4;
        int l15  = lane & 15;
        int m0   = blk * 16;
        const __hip_bfloat16* as = St + l15 * SKL + quad * 8;
        const __hip_bfloat16* bp = wtb2 + (size_t)(wave * 16 + l15) * SW + quad * 8;
        f32x4_t accd = {0.f, 0.f, 0.f, 0.f};
#pragma unroll
        for (int k = 0; k < 29; ++k) {
            bf16x8_t aa = *(const bf16x8_t*)(as + k * 32);
            bf16x8_t bb = *(const bf16x8_t*)(bp + k * 32);
            accd = __builtin_amdgcn_mfma_f32_16x16x32_bf16(aa, bb, accd, 0, 0, 0);
        }
        int c = wave * 16 + l15;
        if (c < N_HIDDEN) {                            // wave 6 covers cols 96..99
#pragma unroll
            for (int rr = 0; rr < 4; ++rr)
                out[(size_t)(m0 + quad * 4 + rr) * N_HIDDEN + c] = accd[rr];
        }
    }
}

extern "C" void kernel_launch(void* const* d_in, const int* in_sizes, int n_in,
                              void* d_out, int out_size, void* d_ws, size_t ws_size,
                              hipStream_t stream) {
    const float* pf  = (const float*)d_in[0];   // (64000, 8)
    const float* af  = (const float*)d_in[1];   // (16000, 100)
    const int*   a2p = (const int*)d_in[2];     // (64000, 2)
    const float* W   = (const float*)d_in[3];   // (8, 10000)
    const float* b   = (const float*)d_in[4];   // (10000,)
    float* out = (float*)d_out;                 // (16000, 100) fp32

    char* ws = (char*)d_ws;
    __hip_bfloat16* wtb2 = (__hip_bfloat16*)ws;                 // 112*1024*2 = 229,376 B
    int* deg             = (int*)(ws + 229376);                 //    64,000 B
    unsigned* bucket     = (unsigned*)(ws + 229376 + 64000);    // 16000*32*4 = 2,048,000 B

    hipMemsetAsync(deg, 0, N_ATOMS * sizeof(int), stream);
    setup_hist<<<SETUP_BLOCKS + HIST_BLOCKS, 256, 0, stream>>>(W, b, a2p, wtb2, deg, bucket);
    fused_edge_gemm<<<N_ATOMS / 16, 512, 0, stream>>>(af, pf, deg, bucket, wtb2, out);
}